// Round 12
// baseline (109.580 us; speedup 1.0000x reference)
//
#include <hip/hip_runtime.h>
#include <stdint.h>

#define T_LEN 524288
#define SEG 8
#define WARM 8
#define EPC (SEG + WARM + 1)   // 17 staged (t,x) entries per chain
#define CHAINS 16
#define GSP (CHAINS * SEG)     // 128 spikes per group
#define CBLK 704               // wave-pairs (each wave = 2 groups)

typedef short short8 __attribute__((ext_vector_type(8)));
typedef float f4 __attribute__((ext_vector_type(4)));
#define KEEPA(v) asm volatile("" : "+v"(v))

// ---- workspace layout (bytes) ----
static const size_t OFF_MASK = 0;                      // T uint8
static const size_t OFF_CNT  = T_LEN;                  // 512 int
static const size_t OFF_N    = T_LEN + 4096;           // 1 int
static const size_t OFF_SPK  = T_LEN + 8192;           // T int

__device__ __forceinline__ short bfr(float f) {        // fp32 -> bf16 RNE
    uint32_t u = __float_as_uint(f);
    u = (u + 0x7fffu + ((u >> 16) & 1u)) >> 16;
    return (short)u;
}
__device__ __forceinline__ unsigned pk(float hi, float lo) {
    return (((unsigned)(unsigned short)bfr(hi)) << 16) | (unsigned short)bfr(lo);
}

// ---- K1: spike mask (fp32 rolling window RMS) + per-1024-block count ----
__global__ __launch_bounds__(256) void k_mask(const float* __restrict__ x,
                                              uint8_t* __restrict__ mask,
                                              float* __restrict__ out, int out_size,
                                              int* __restrict__ cnt)
{
    __shared__ float tile[1154];
    __shared__ int tot;
    const int bs = blockIdx.x * 1024;
    const int tid = threadIdx.x;
    if (tid == 0) tot = 0;
    for (int j = tid; j < 1154; j += 256) {
        int g = bs - 130 + j;
        tile[j] = (g >= 0) ? x[g] : 0.f;
    }
    __syncthreads();
    const int loc = tid * 4;
    float s = 0.f;
    #pragma unroll 16
    for (int m = 0; m < 128; ++m) { float v = tile[loc + 2 + m]; s = fmaf(v, v, s); }
    uchar4 mv; float4 mf; int msum = 0;
    uint8_t* mp = &mv.x; float* fp = &mf.x;
    #pragma unroll
    for (int it = 0; it < 4; ++it) {
        int t = bs + loc + it;
        int c = t < 128 ? (t < 1 ? 1 : t) : 128;
        float rms = sqrtf(fmaxf(s, 0.f) / (float)c) + 1e-8f;
        float xt = tile[loc + 130 + it];
        float pr = 2.f * tile[loc + 129 + it] - tile[loc + 128 + it];
        bool m = (t < 2) || (fabsf(xt - pr) > 2.5f * rms);
        mp[it] = m ? 1 : 0; fp[it] = m ? 1.f : 0.f; msum += m ? 1 : 0;
        float a = tile[loc + 130 + it], d = tile[loc + 2 + it];
        s = fmaf(a, a, s) - d * d;
    }
    *(uchar4*)(mask + bs + loc) = mv;
    int oi = T_LEN + 1 + bs + loc;
    if (oi + 3 < out_size) *(float4*)(out + oi) = mf;
    for (int d = 32; d; d >>= 1) msum += __shfl_down(msum, d, 64);
    if ((tid & 63) == 0) atomicAdd(&tot, msum);
    __syncthreads();
    if (tid == 0) cnt[blockIdx.x] = tot;
}

// ---- K2: scatter (with inline global prefix over cnt[]) ----
__global__ __launch_bounds__(256) void k_scatter(const uint8_t* __restrict__ mask,
                                                 const int* __restrict__ cnt,
                                                 int* __restrict__ spk,
                                                 int* __restrict__ nspk,
                                                 float* __restrict__ out)
{
    __shared__ int wtot[4];
    __shared__ int sh_base;
    const int tid = threadIdx.x, b = blockIdx.x;
    const int lane = tid & 63, w = tid >> 6;
    const int base = b * 1024 + tid * 4;
    uchar4 mv = *(const uchar4*)(mask + base);
    int m0 = mv.x, m1 = mv.y, m2 = mv.z, m3 = mv.w;
    int e1 = m0, e2 = m0 + m1, e3 = m0 + m1 + m2, tsum = e3 + m3;
    int incl = tsum;
    for (int d = 1; d < 64; d <<= 1) {
        int u = __shfl_up(incl, d, 64);
        if (lane >= d) incl += u;
    }
    if (lane == 63) wtot[w] = incl;

    // wave 0: global prefix = sum cnt[0..b)
    if (w == 0) {
        int pre = 0;
        #pragma unroll
        for (int k8 = 0; k8 < 8; ++k8) {
            int idx = k8 * 64 + lane;
            pre += (idx < b) ? cnt[idx] : 0;
        }
        for (int d = 32; d; d >>= 1) pre += __shfl_down(pre, d, 64);
        if (lane == 0) sh_base = pre;
    }
    __syncthreads();
    int woff = 0;
    for (int i = 0; i < w; i++) woff += wtot[i];
    int texcl = woff + incl - tsum;
    int g = sh_base + texcl;
    int e[4] = {0, e1, e2, e3};
    int m[4] = {m0, m1, m2, m3};
    #pragma unroll
    for (int k = 0; k < 4; k++) {
        if (m[k]) spk[g + e[k]] = base + k;
    }
    if (b == 511 && tid == 0) {
        int N = sh_base + wtot[0] + wtot[1] + wtot[2] + wtot[3];
        *nspk = N;
        out[T_LEN] = (float)N;
    }
}

// ---- K3: MFMA-batched GRU chains, 2 groups per wave (software pipelined) ----
// Layouts HW-verified in R10/R11. C->B transpose via 8 ds_bpermute + 4 cndmask
// (no LDS round trip). a,b via A3 MFMA tile.
__global__ __attribute__((amdgpu_waves_per_eu(1)))
__launch_bounds__(64)
void k_chain(const float* __restrict__ Whh,
             const float* __restrict__ Wih,
             const float* __restrict__ bih,
             const float* __restrict__ bhh,
             const int* __restrict__ spk,
             const float* __restrict__ x,
             const int* __restrict__ nspk,
             const float* __restrict__ Wv,
             const float* __restrict__ bv,
             const float* __restrict__ Wsc,
             const float* __restrict__ bs,
             float* __restrict__ out)
{
    __shared__ float2 st[2][CHAINS * EPC];
    __shared__ float  ab[2][2 * GSP];

    const int lane = threadIdx.x;
    const int m = lane & 15;
    const int quad = lane >> 4;
    const int N = *nspk;

    // ---- A fragments (static): A[m][k], k = 8*quad + j ----
    short8 A1[6], A2[6], A3;
    #pragma unroll
    for (int t = 0; t < 6; ++t) {
        union { short s[8]; short8 v; } u1, u2;
        int rowg = 16 * t + m;
        #pragma unroll
        for (int j = 0; j < 8; ++j) {
            int k = 8 * quad + j;
            u1.s[j] = bfr(Whh[rowg * 32 + k]);
            float a2v = 0.f;
            if (k == 0) a2v = Wih[rowg * 2];
            else if (k == 1) a2v = Wih[rowg * 2 + 1];
            else if (k == 2) a2v = (rowg < 64) ? (bih[rowg] + bhh[rowg]) : bih[rowg];
            u2.s[j] = bfr(a2v);
        }
        A1[t] = u1.v; A2[t] = u2.v;
    }
    {
        union { short s[8]; short8 v; } u3;
        #pragma unroll
        for (int j = 0; j < 8; ++j) {
            int k = 8 * quad + j;
            float v = (m == 0) ? Wv[k] : (m == 1) ? Wsc[k] : 0.f;
            u3.s[j] = bfr(v);
        }
        A3 = u3.v;
    }
    #pragma unroll
    for (int t = 0; t < 6; ++t) { KEEPA(A1[t]); KEEPA(A2[t]); }
    KEEPA(A3);

    float bn0[4], bn1[4];
    #pragma unroll
    for (int e = 0; e < 4; ++e) {
        int r0 = quad * 4 + e;
        bn0[e] = bhh[64 + r0];  bn1[e] = bhh[80 + r0];
    }
    const float bv0 = bv[0], bs0 = bs[0];

    // bpermute transpose addresses (static): srcA/srcB lanes for this lane
    const int aA = ((((2 * quad) & 3) * 16 + m) << 2);
    const int aB = ((((2 * quad + 1) & 3) * 16 + m) << 2);
    const bool ql = (quad < 2);

    for (int gp = blockIdx.x; (2 * gp) * GSP < N; gp += CBLK) {
        const int base0 = 2 * gp * GSP;          // group g: base0 + g*GSP
        // ---- stage both groups ----
        #pragma unroll
        for (int g = 0; g < 2; ++g) {
            for (int e = lane; e < CHAINS * EPC; e += 64) {
                int n = e / EPC, j = e - n * EPC;
                int s = base0 + g * GSP + n * SEG - (WARM + 1) + j;
                s = min(max(s, 0), N - 1);
                int t = spk[s];
                st[g][e] = make_float2((float)t, x[t]);
            }
        }
        __builtin_amdgcn_wave_barrier();

        float h0[2][4], h1[2][4], tprev[2];
        short8 B1[2];
        float2 cur[2];
        #pragma unroll
        for (int g = 0; g < 2; ++g) {
            #pragma unroll
            for (int e = 0; e < 4; ++e) { h0[g][e] = 0.f; h1[g][e] = 0.f; }
            B1[g] = (short8)0;
            tprev[g] = st[g][m * EPC].x;
            cur[g] = st[g][m * EPC + 1];
        }

        for (int j = 0; j < SEG + WARM; ++j) {
            f4 z4 = {0.f, 0.f, 0.f, 0.f};
            f4 Drz[2][4], Dh0[2], Dh1[2], Di0[2], Di1[2];
            float2 nxt[2];
            #pragma unroll
            for (int g = 0; g < 2; ++g) {
                float xt = cur[g].y;
                float d = (cur[g].x - tprev[g]) * 0.0078125f;
                tprev[g] = cur[g].x;
                nxt[g] = st[g][m * EPC + min(j + 2, EPC - 1)];

                unsigned p0 = (__float_as_uint(d) & 0xFFFF0000u) | (__float_as_uint(xt) >> 16);
                unsigned p1 = 0x00003F80u;
                p0 = (quad == 0) ? p0 : 0u;
                p1 = (quad == 0) ? p1 : 0u;
                union { unsigned u[4]; short8 v; } b2u;
                b2u.u[0] = p0; b2u.u[1] = p1; b2u.u[2] = 0u; b2u.u[3] = 0u;
                short8 B2 = b2u.v;

                f4 t0 = __builtin_amdgcn_mfma_f32_16x16x32_bf16(A2[0], B2, z4, 0, 0, 0);
                f4 t1 = __builtin_amdgcn_mfma_f32_16x16x32_bf16(A2[1], B2, z4, 0, 0, 0);
                f4 t2 = __builtin_amdgcn_mfma_f32_16x16x32_bf16(A2[2], B2, z4, 0, 0, 0);
                f4 t3 = __builtin_amdgcn_mfma_f32_16x16x32_bf16(A2[3], B2, z4, 0, 0, 0);
                Di0[g] = __builtin_amdgcn_mfma_f32_16x16x32_bf16(A2[4], B2, z4, 0, 0, 0);
                Di1[g] = __builtin_amdgcn_mfma_f32_16x16x32_bf16(A2[5], B2, z4, 0, 0, 0);
                Drz[g][0] = __builtin_amdgcn_mfma_f32_16x16x32_bf16(A1[0], B1[g], t0, 0, 0, 0);
                Drz[g][1] = __builtin_amdgcn_mfma_f32_16x16x32_bf16(A1[1], B1[g], t1, 0, 0, 0);
                Drz[g][2] = __builtin_amdgcn_mfma_f32_16x16x32_bf16(A1[2], B1[g], t2, 0, 0, 0);
                Drz[g][3] = __builtin_amdgcn_mfma_f32_16x16x32_bf16(A1[3], B1[g], t3, 0, 0, 0);
                Dh0[g] = __builtin_amdgcn_mfma_f32_16x16x32_bf16(A1[4], B1[g], z4, 0, 0, 0);
                Dh1[g] = __builtin_amdgcn_mfma_f32_16x16x32_bf16(A1[5], B1[g], z4, 0, 0, 0);
            }

            #pragma unroll
            for (int g = 0; g < 2; ++g) {
                #pragma unroll
                for (int e = 0; e < 4; ++e) {
                    float r0 = __builtin_amdgcn_rcpf(1.f + __builtin_amdgcn_exp2f(-1.44269504089f * Drz[g][0][e]));
                    float r1 = __builtin_amdgcn_rcpf(1.f + __builtin_amdgcn_exp2f(-1.44269504089f * Drz[g][1][e]));
                    float zz0 = __builtin_amdgcn_rcpf(1.f + __builtin_amdgcn_exp2f(-1.44269504089f * Drz[g][2][e]));
                    float zz1 = __builtin_amdgcn_rcpf(1.f + __builtin_amdgcn_exp2f(-1.44269504089f * Drz[g][3][e]));
                    float np0 = fmaf(r0, Dh0[g][e] + bn0[e], Di0[g][e]);
                    float np1 = fmaf(r1, Dh1[g][e] + bn1[e], Di1[g][e]);
                    float en0 = __builtin_amdgcn_exp2f(2.88539008178f * np0);
                    float en1 = __builtin_amdgcn_exp2f(2.88539008178f * np1);
                    float n0 = fmaf(-2.f, __builtin_amdgcn_rcpf(1.f + en0), 1.f);
                    float n1 = fmaf(-2.f, __builtin_amdgcn_rcpf(1.f + en1), 1.f);
                    h0[g][e] = fmaf(zz0, h0[g][e] - n0, n0);
                    h1[g][e] = fmaf(zz1, h1[g][e] - n1, n1);
                }

                // C->B transpose via bpermute (no LDS round trip)
                unsigned p0 = pk(h0[g][1], h0[g][0]);
                unsigned p1 = pk(h0[g][3], h0[g][2]);
                unsigned p2 = pk(h1[g][1], h1[g][0]);
                unsigned p3 = pk(h1[g][3], h1[g][2]);
                unsigned tA0 = __builtin_amdgcn_ds_bpermute(aA, (int)p0);
                unsigned tA1 = __builtin_amdgcn_ds_bpermute(aA, (int)p1);
                unsigned tA2 = __builtin_amdgcn_ds_bpermute(aA, (int)p2);
                unsigned tA3 = __builtin_amdgcn_ds_bpermute(aA, (int)p3);
                unsigned tB0 = __builtin_amdgcn_ds_bpermute(aB, (int)p0);
                unsigned tB1 = __builtin_amdgcn_ds_bpermute(aB, (int)p1);
                unsigned tB2 = __builtin_amdgcn_ds_bpermute(aB, (int)p2);
                unsigned tB3 = __builtin_amdgcn_ds_bpermute(aB, (int)p3);
                union { unsigned u[4]; short8 v; } bu;
                bu.u[0] = ql ? tA0 : tA2;
                bu.u[1] = ql ? tA1 : tA3;
                bu.u[2] = ql ? tB0 : tB2;
                bu.u[3] = ql ? tB1 : tB3;
                B1[g] = bu.v;

                if (j >= WARM) {
                    f4 Dab = __builtin_amdgcn_mfma_f32_16x16x32_bf16(A3, B1[g], z4, 0, 0, 0);
                    int sg = base0 + g * GSP + m * SEG + (j - WARM);
                    if (quad == 0 && sg < N)
                        *(float2*)&ab[g][2 * (m * SEG + j - WARM)] =
                            make_float2(Dab[0] + bv0, Dab[1] + bs0);
                }
                cur[g] = nxt[g];
            }
        }
        __builtin_amdgcn_wave_barrier();

        // ---- expansion: spike s fills out[t] for t in [t_s, t_next) ----
        #pragma unroll
        for (int g = 0; g < 2; ++g) {
            const int bg = base0 + g * GSP;
            if (bg >= N) break;
            const int nid = bg + GSP;
            const int tN = (nid >= N) ? T_LEN : spk[nid];
            #pragma unroll
            for (int h = 0; h < 2; ++h) {
                int sl = lane + 64 * h;
                int sg = bg + sl;
                if (sg < N) {
                    int n = sl >> 3, jj = sl & 7;
                    float ts = st[g][n * EPC + (WARM + 1) + jj].x;
                    int tnext;
                    if (sg + 1 >= N) tnext = T_LEN;
                    else if (sl + 1 < GSP) {
                        int n2 = (sl + 1) >> 3, j2 = (sl + 1) & 7;
                        tnext = (int)st[g][n2 * EPC + (WARM + 1) + j2].x;
                    } else tnext = tN;
                    float2 abv = *(const float2*)&ab[g][2 * sl];
                    int tsi = (int)ts;
                    for (int t = tsi; t < tnext; ++t)
                        out[t] = fmaf(abv.y, (float)(t - tsi) * 0.0078125f, abv.x);
                }
            }
        }
        __builtin_amdgcn_wave_barrier();
    }
}

extern "C" void kernel_launch(void* const* d_in, const int* in_sizes, int n_in,
                              void* d_out, int out_size, void* d_ws, size_t ws_size,
                              hipStream_t stream)
{
    const float* x   = (const float*)d_in[0];
    const float* Wih = (const float*)d_in[1];
    const float* Whh = (const float*)d_in[2];
    const float* bih = (const float*)d_in[3];
    const float* bhh = (const float*)d_in[4];
    const float* Wv  = (const float*)d_in[5];
    const float* bv  = (const float*)d_in[6];
    const float* Wsc = (const float*)d_in[7];
    const float* bs  = (const float*)d_in[8];
    float* out = (float*)d_out;

    char* ws = (char*)d_ws;
    uint8_t* mask = (uint8_t*)(ws + OFF_MASK);
    int* cnt  = (int*)(ws + OFF_CNT);
    int* nspk = (int*)(ws + OFF_N);
    int* spk  = (int*)(ws + OFF_SPK);

    k_mask<<<512, 256, 0, stream>>>(x, mask, out, out_size, cnt);
    k_scatter<<<512, 256, 0, stream>>>(mask, cnt, spk, nspk, out);
    k_chain<<<CBLK, 64, 0, stream>>>(Whh, Wih, bih, bhh, spk, x, nspk,
                                     Wv, bv, Wsc, bs, out);
}